// Round 4
// baseline (103.959 us; speedup 1.0000x reference)
//
#include <hip/hip_runtime.h>
#include <hip/hip_bf16.h>
#include <stdint.h>

#define NB 2
#define LQ 2048
#define DMODEL 1024
#define NH 8
#define DH 128
#define KWIN 64

typedef __attribute__((ext_vector_type(8))) short short8;
typedef __attribute__((ext_vector_type(4))) float f32x4;

__device__ __forceinline__ ushort f2bf(float f) {
  uint u = __float_as_uint(f);
  return (ushort)((u + 0x7fffu + ((u >> 16) & 1u)) >> 16);
}
__device__ __forceinline__ float bflo(uint u) { return __uint_as_float(u << 16); }
__device__ __forceinline__ float bfhi(uint u) { return __uint_as_float(u & 0xffff0000u); }

// ---------------- merged f32 -> bf16 conversion (7 arrays, one launch) ----------------
// dst regions are contiguous in ws in this exact order: q,k,v (n4in each), Wq,Wk,Wv,Wc (n4w each).
__global__ void cvt_all(const float4* __restrict__ q, const float4* __restrict__ k,
                        const float4* __restrict__ v, const float4* __restrict__ wq,
                        const float4* __restrict__ wk, const float4* __restrict__ wv,
                        const float4* __restrict__ wc, ushort4* __restrict__ dst) {
  const int n4in = (NB * LQ * DMODEL) / 4;   // 2^20
  const int n4w = (NH * DH * DMODEL) / 4;    // 2^18
  const int total = 3 * n4in + 4 * n4w;
  const int stride = gridDim.x * blockDim.x;
  for (int i = blockIdx.x * blockDim.x + threadIdx.x; i < total; i += stride) {
    const float4* src;
    int off;
    if (i < 3 * n4in) {
      const int r = i >> 20;
      off = i & (n4in - 1);
      src = (r == 0) ? q : ((r == 1) ? k : v);
    } else {
      const int j = i - 3 * n4in;
      const int r = j >> 18;
      off = j & (n4w - 1);
      src = (r == 0) ? wq : ((r == 1) ? wk : ((r == 2) ? wv : wc));
    }
    float4 x = src[off];
    dst[i] = make_ushort4(f2bf(x.x), f2bf(x.y), f2bf(x.z), f2bf(x.w));
  }
}

// ---------------- QKV GEMM: 256x256 tile, BK=32, 4-slot LDS ring, counted vmcnt ----------
// C[M,N] = A[M,K] * Bt[N,K]^T + bias[N], bf16 out. 8 waves (2M x 4N), per-wave 128x64.
// Ring schedule per K-tile t: STAGE(t+3) ; vmcnt(12) ; barrier ; ds_read frags ;
// lgkmcnt(0) ; barrier ; 32 MFMA.  (3 tiles in flight, never drains to 0 mid-loop.)
__global__ __launch_bounds__(512, 2) void gemm256_qkv(
    const ushort* __restrict__ A0, const ushort* __restrict__ B0,
    const float* __restrict__ c0, ushort* __restrict__ D0,
    const ushort* __restrict__ A1, const ushort* __restrict__ B1,
    const float* __restrict__ c1, ushort* __restrict__ D1,
    const ushort* __restrict__ A2, const ushort* __restrict__ B2,
    const float* __restrict__ c2, ushort* __restrict__ D2,
    int M, int N, int Kd) {
  // XCD-chunked bijective swizzle over flat grid (192 blocks, 24/XCD)
  const int gx = gridDim.x, gy = gridDim.y;
  const int nblk = gx * gy * gridDim.z;
  const int fid = (blockIdx.z * gy + blockIdx.y) * gx + blockIdx.x;
  const int cpx = nblk >> 3;
  const int nid = (fid & 7) * cpx + (fid >> 3);
  const int z = nid / (gx * gy);
  const int rem = nid % (gx * gy);
  const int m0 = (rem / gx) * 256;
  const int n0 = (rem % gx) * 256;

  const ushort* A = (z == 0) ? A0 : ((z == 1) ? A1 : A2);
  const ushort* Bt = (z == 0) ? B0 : ((z == 1) ? B1 : B2);
  const float* bias = (z == 0) ? c0 : ((z == 1) ? c1 : c2);
  ushort* Cv = (z == 0) ? D0 : ((z == 1) ? D1 : D2);

  // slot layout (ushorts): [slot][A half0 4096 | A half1 4096 | B half0 4096 | B half1 4096]
  __shared__ ushort LDS[4 * 16384];  // 128 KB

  const int tid = threadIdx.x;
  const int wave = tid >> 6, lane = tid & 63;
  const int wm = wave >> 2, wn = wave & 3;
  const int lrow = lane & 15, kgrp = lane >> 4;

  // staging geometry: thread covers 16B at byte b of each 8KB round
  const int b = tid * 16;
  const int srow = b >> 6;          // row within 128-row half (64B per row)
  const int scc = (b & 63) >> 1;    // k-elem within row

  const ushort* gA0 = A + (size_t)(m0 + srow) * Kd + scc;
  const ushort* gA1 = A + (size_t)(m0 + 128 + srow) * Kd + scc;
  const ushort* gB0 = Bt + (size_t)(n0 + srow) * Kd + scc;
  const ushort* gB1 = Bt + (size_t)(n0 + 128 + srow) * Kd + scc;
  const int dso = b >> 1;  // ushort offset within a 4096-ushort quarter

  auto STAGE = [&](int slot, int kt) {
    ushort* sl = LDS + slot * 16384;
    __builtin_amdgcn_global_load_lds(
        (const __attribute__((address_space(1))) void*)(gA0 + kt),
        (__attribute__((address_space(3))) void*)(sl + dso), 16, 0, 0);
    __builtin_amdgcn_global_load_lds(
        (const __attribute__((address_space(1))) void*)(gA1 + kt),
        (__attribute__((address_space(3))) void*)(sl + 4096 + dso), 16, 0, 0);
    __builtin_amdgcn_global_load_lds(
        (const __attribute__((address_space(1))) void*)(gB0 + kt),
        (__attribute__((address_space(3))) void*)(sl + 8192 + dso), 16, 0, 0);
    __builtin_amdgcn_global_load_lds(
        (const __attribute__((address_space(1))) void*)(gB1 + kt),
        (__attribute__((address_space(3))) void*)(sl + 12288 + dso), 16, 0, 0);
  };

  f32x4 acc[8][4] = {};
  const int NT = Kd >> 5;  // 32 K-tiles

  STAGE(0, 0);
  STAGE(1, 32);
  STAGE(2, 64);

  for (int t = 0; t < NT; ++t) {
    const int pf = t + 3;
    if (pf < NT) {
      STAGE(pf & 3, pf << 5);
      asm volatile("s_waitcnt vmcnt(12)" ::: "memory");
    } else if (pf == NT) {
      asm volatile("s_waitcnt vmcnt(8)" ::: "memory");
    } else if (pf == NT + 1) {
      asm volatile("s_waitcnt vmcnt(4)" ::: "memory");
    } else {
      asm volatile("s_waitcnt vmcnt(0)" ::: "memory");
    }
    __builtin_amdgcn_s_barrier();           // tile t visible to all waves
    __builtin_amdgcn_sched_barrier(0);

    const ushort* sA = LDS + (t & 3) * 16384 + wm * 4096 + lrow * 32 + kgrp * 8;
    const ushort* sB = LDS + (t & 3) * 16384 + 8192 + (wn >> 1) * 4096 +
                       ((wn & 1) * 64 + lrow) * 32 + kgrp * 8;
    short8 af[8], bfr[4];
#pragma unroll
    for (int m = 0; m < 8; ++m) af[m] = *(const short8*)(sA + m * 512);
#pragma unroll
    for (int n = 0; n < 4; ++n) bfr[n] = *(const short8*)(sB + n * 512);
    asm volatile("s_waitcnt lgkmcnt(0)" ::: "memory");
    __builtin_amdgcn_sched_barrier(0);
    __builtin_amdgcn_s_barrier();           // all waves done reading slot t&3

#pragma unroll
    for (int m = 0; m < 8; ++m)
#pragma unroll
      for (int n = 0; n < 4; ++n)
        acc[m][n] = __builtin_amdgcn_mfma_f32_16x16x32_bf16(af[m], bfr[n], acc[m][n], 0, 0, 0);
  }

  // epilogue: C/D layout col=lane&15, row=(lane>>4)*4+j
  const int cbase = n0 + wn * 64;
  const int rbase = m0 + wm * 128;
  float bv[4];
#pragma unroll
  for (int n = 0; n < 4; ++n) bv[n] = bias[cbase + n * 16 + lrow];

#pragma unroll
  for (int m = 0; m < 8; ++m) {
#pragma unroll
    for (int n = 0; n < 4; ++n) {
      const int col = cbase + n * 16 + lrow;
#pragma unroll
      for (int j = 0; j < 4; ++j) {
        const int row = rbase + m * 16 + kgrp * 4 + j;
        Cv[(size_t)row * N + col] = f2bf(acc[m][n][j] + bv[n]);
      }
    }
  }
}

// ---------------- out-proj GEMM: 128x128 tile, 2-phase dbuf (proven) ----------------
__global__ __launch_bounds__(256, 4) void gemm_out(
    const ushort* __restrict__ A, const ushort* __restrict__ Bt,
    const float* __restrict__ bias, float* __restrict__ Cv, int M, int N, int Kd) {
  const int gx = gridDim.x, gy = gridDim.y;
  const int nblk = gx * gy;
  const int fid = blockIdx.y * gx + blockIdx.x;
  const int cpx = nblk >> 3;
  const int nid = (fid & 7) * cpx + (fid >> 3);
  const int m0 = (nid / gx) * 128;
  const int n0 = (nid % gx) * 128;

  __shared__ ushort As[2][128 * 32];
  __shared__ ushort Bs[2][128 * 32];

  const int tid = threadIdx.x;
  const int wave = tid >> 6, lane = tid & 63;
  const int wm = wave >> 1, wn = wave & 1;
  const int lrow = lane & 15, kgrp = lane >> 4;

  const int b0 = tid * 16;
  const int b1 = b0 + 4096;
  const int r0 = b0 >> 6, cc0 = (b0 & 63) >> 1;
  const int r1 = b1 >> 6, cc1 = (b1 & 63) >> 1;

  const ushort* gA0 = A + (size_t)(m0 + r0) * Kd + cc0;
  const ushort* gA1 = A + (size_t)(m0 + r1) * Kd + cc1;
  const ushort* gB0 = Bt + (size_t)(n0 + r0) * Kd + cc0;
  const ushort* gB1 = Bt + (size_t)(n0 + r1) * Kd + cc1;

  auto stage = [&](int buf, int kt) {
    __builtin_amdgcn_global_load_lds(
        (const __attribute__((address_space(1))) void*)(gA0 + kt),
        (__attribute__((address_space(3))) void*)(As[buf] + (b0 >> 1)), 16, 0, 0);
    __builtin_amdgcn_global_load_lds(
        (const __attribute__((address_space(1))) void*)(gA1 + kt),
        (__attribute__((address_space(3))) void*)(As[buf] + (b1 >> 1)), 16, 0, 0);
    __builtin_amdgcn_global_load_lds(
        (const __attribute__((address_space(1))) void*)(gB0 + kt),
        (__attribute__((address_space(3))) void*)(Bs[buf] + (b0 >> 1)), 16, 0, 0);
    __builtin_amdgcn_global_load_lds(
        (const __attribute__((address_space(1))) void*)(gB1 + kt),
        (__attribute__((address_space(3))) void*)(Bs[buf] + (b1 >> 1)), 16, 0, 0);
  };

  f32x4 acc[4][4] = {};

  auto compute = [&](int buf) {
    short8 af[4], bfr[4];
#pragma unroll
    for (int m = 0; m < 4; ++m)
      af[m] = *(const short8*)(As[buf] + (wm * 64 + m * 16 + lrow) * 32 + kgrp * 8);
#pragma unroll
    for (int n = 0; n < 4; ++n)
      bfr[n] = *(const short8*)(Bs[buf] + (wn * 64 + n * 16 + lrow) * 32 + kgrp * 8);
#pragma unroll
    for (int m = 0; m < 4; ++m)
#pragma unroll
      for (int n = 0; n < 4; ++n)
        acc[m][n] = __builtin_amdgcn_mfma_f32_16x16x32_bf16(af[m], bfr[n], acc[m][n], 0, 0, 0);
  };

  const int nt = Kd >> 5;
  stage(0, 0);
  __syncthreads();
  int cur = 0;
  for (int it = 0; it < nt - 1; ++it) {
    stage(cur ^ 1, (it + 1) << 5);
    compute(cur);
    __syncthreads();
    cur ^= 1;
  }
  compute(cur);

  const int cbase = n0 + wn * 64;
  const int rbase = m0 + wm * 64;
  float bv[4];
#pragma unroll
  for (int n = 0; n < 4; ++n) bv[n] = bias[cbase + n * 16 + lrow];

#pragma unroll
  for (int m = 0; m < 4; ++m) {
#pragma unroll
    for (int n = 0; n < 4; ++n) {
      const int col = cbase + n * 16 + lrow;
#pragma unroll
      for (int j = 0; j < 4; ++j) {
        const int row = rbase + m * 16 + kgrp * 4 + j;
        Cv[(size_t)row * N + col] = acc[m][n][j] + bv[n];
      }
    }
  }
}

// ---------------- banded attention via residue-class MFMA flash ----------------
__global__ __launch_bounds__(128) void banded_attn_mfma(
    const ushort* __restrict__ qp, const ushort* __restrict__ kp,
    const ushort* __restrict__ vp, ushort* __restrict__ ao) {
  __shared__ ushort Qs[32 * 128];
  __shared__ ushort Ks[96 * 128];
  __shared__ ushort Vs[112 * 128];
  __shared__ ushort Ps[2][16 * 104];
  __shared__ ushort Os[2][16 * 128];

  const int tid = threadIdx.x;
  const int wv = tid >> 6;
  const int lane = tid & 63;
  const int lrow = lane & 15, kgrp = lane >> 4;

  const int blk = blockIdx.x;
  const int chunk = blk & 63;
  const int h = (blk >> 6) & 7;
  const int b = blk >> 9;
  const int sh = h >> 1;
  const int dil = 1 << sh;
  const int Ld = LQ >> sh;
  const int rres = chunk >> (6 - sh);
  const int tile = chunk & ((64 >> sh) - 1);
  const int t0 = tile << 5;
  const int p0 = t0 - 32;

  const size_t headoff = (size_t)h * DH;
  const size_t bbase = (size_t)b * LQ * (NH * DH);

  const int srow = lane >> 4;
  const int sc = lane & 15;
  for (int it = wv; it < 60; it += 2) {
    int rbase, pstart;
    const ushort* g;
    ushort* ld;
    if (it < 8) {
      rbase = it * 4; pstart = t0; g = qp; ld = Qs;
    } else if (it < 32) {
      rbase = (it - 8) * 4; pstart = p0; g = kp; ld = Ks;
    } else {
      rbase = (it - 32) * 4; pstart = p0; g = vp; ld = Vs;
    }
    int row = rbase + srow;
    int key = (row ^ (row >> 3)) & 7;
    int cs = sc ^ key;
    int t = pstart + row;
    t = t < 0 ? 0 : (t >= Ld ? Ld - 1 : t);
    int l = rres + t * dil;
    const ushort* src = g + bbase + (size_t)l * (NH * DH) + headoff + cs * 8;
    __builtin_amdgcn_global_load_lds(
        (const __attribute__((address_space(1))) void*)src,
        (__attribute__((address_space(3))) void*)(ld + rbase * 128), 16, 0, 0);
  }
  __syncthreads();

  const int iblk = wv << 4;
  f32x4 accs[5] = {};
#pragma unroll
  for (int ks = 0; ks < 4; ++ks) {
    const int qrow = iblk + lrow;
    const int qslot = (ks * 4 + kgrp) ^ ((qrow ^ (qrow >> 3)) & 7);
    short8 qf = *(const short8*)(Qs + qrow * 128 + qslot * 8);
#pragma unroll
    for (int t = 0; t < 5; ++t) {
      const int krow = (wv + t) * 16 + lrow;
      const int kslot = (ks * 4 + kgrp) ^ ((krow ^ (krow >> 3)) & 7);
      short8 kf = *(const short8*)(Ks + krow * 128 + kslot * 8);
      accs[t] = __builtin_amdgcn_mfma_f32_16x16x32_bf16(qf, kf, accs[t], 0, 0, 0);
    }
  }

  float dens[4];
#pragma unroll
  for (int j = 0; j < 4; ++j) {
    const int i_b = iblk + kgrp * 4 + j;
    float mj = -1e30f;
#pragma unroll
    for (int t = 0; t < 5; ++t) {
      const int jj = (wv + t) * 16 + lrow;
      const int p = p0 + jj;
      const bool ok = (jj >= i_b + 1) && (jj <= i_b + 64) && (p >= 0) && (p < Ld);
      float v = ok ? accs[t][j] : -1e30f;
      accs[t][j] = v;
      mj = fmaxf(mj, v);
    }
#pragma unroll
    for (int off = 1; off < 16; off <<= 1) mj = fmaxf(mj, __shfl_xor(mj, off));
    float dj = 0.f;
#pragma unroll
    for (int t = 0; t < 5; ++t) {
      float e = __expf(accs[t][j] - mj);
      accs[t][j] = e;
      dj += e;
    }
#pragma unroll
    for (int off = 1; off < 16; off <<= 1) dj += __shfl_xor(dj, off);
    dens[j] = dj;
  }

  ushort* Pw = Ps[wv];
#pragma unroll
  for (int j = 0; j < 4; ++j) {
    const int prow = kgrp * 4 + j;
#pragma unroll
    for (int t = 0; t < 5; ++t) Pw[prow * 104 + t * 16 + lrow] = f2bf(accs[t][j]);
    Pw[prow * 104 + 80 + lrow] = 0;
  }

  f32x4 accv[8] = {};
#pragma unroll
  for (int ks = 0; ks < 3; ++ks) {
    short8 pf = *(const short8*)(Pw + lrow * 104 + ks * 32 + kgrp * 8);
#pragma unroll
    for (int dt = 0; dt < 8; ++dt) {
      short8 vf;
#pragma unroll
      for (int rr = 0; rr < 8; ++rr) {
        const int vrow = iblk + ks * 32 + kgrp * 8 + rr;
        const int d = dt * 16 + lrow;
        const int slot = (d >> 3) ^ ((vrow ^ (vrow >> 3)) & 7);
        vf[rr] = (short)Vs[vrow * 128 + slot * 8 + (d & 7)];
      }
      accv[dt] = __builtin_amdgcn_mfma_f32_16x16x32_bf16(pf, vf, accv[dt], 0, 0, 0);
    }
  }

  ushort* Ow = Os[wv];
#pragma unroll
  for (int j = 0; j < 4; ++j) {
    const float inv = 1.f / dens[j];
    const int orow = kgrp * 4 + j;
#pragma unroll
    for (int dt = 0; dt < 8; ++dt)
      Ow[orow * 128 + dt * 16 + lrow] = f2bf(accv[dt][j] * inv);
  }
#pragma unroll
  for (int pass = 0; pass < 4; ++pass) {
    const int i_loc = pass * 4 + srow;
    const int tq = t0 + iblk + i_loc;
    const int l = rres + tq * dil;
    short8 vvv = *(const short8*)(Ow + i_loc * 128 + sc * 8);
    *(short8*)(ao + bbase + (size_t)l * (NH * DH) + headoff + sc * 8) = vvv;
  }
}

// ---------------- launch ----------------
extern "C" void kernel_launch(void* const* d_in, const int* in_sizes, int n_in,
                              void* d_out, int out_size, void* d_ws, size_t ws_size,
                              hipStream_t stream) {
  const float* q = (const float*)d_in[0];
  const float* k = (const float*)d_in[1];
  const float* v = (const float*)d_in[2];
  const float* Wq = (const float*)d_in[3];
  const float* bq = (const float*)d_in[4];
  const float* Wk = (const float*)d_in[5];
  const float* bk = (const float*)d_in[6];
  const float* Wv = (const float*)d_in[7];
  const float* bv = (const float*)d_in[8];
  const float* Wc = (const float*)d_in[9];
  const float* bc = (const float*)d_in[10];

  const size_t NIN = (size_t)NB * LQ * DMODEL;
  const size_t NW = (size_t)NH * DH * DMODEL;

  ushort* qin = (ushort*)d_ws;
  ushort* kin = qin + NIN;
  ushort* vin = kin + NIN;
  ushort* wqb = vin + NIN;
  ushort* wkb = wqb + NW;
  ushort* wvb = wkb + NW;
  ushort* wcb = wvb + NW;
  ushort* qp = wcb + NW;
  ushort* kp = qp + NIN;
  ushort* vp = kp + NIN;
  ushort* aob = vp + NIN;

  hipLaunchKernelGGL(cvt_all, dim3(2048), dim3(256), 0, stream,
                     (const float4*)q, (const float4*)k, (const float4*)v,
                     (const float4*)Wq, (const float4*)Wk, (const float4*)Wv,
                     (const float4*)Wc, (ushort4*)qin);

  dim3 g1(DMODEL / 256, (NB * LQ) / 256, 3);  // 4 x 16 x 3 = 192 blocks
  hipLaunchKernelGGL(gemm256_qkv, g1, dim3(512), 0, stream,
                     qin, wqb, bq, qp,
                     kin, wkb, bk, kp,
                     vin, wvb, bv, vp,
                     NB * LQ, DMODEL, DMODEL);

  hipLaunchKernelGGL(banded_attn_mfma, dim3(NB * NH * 64), dim3(128), 0, stream,
                     qp, kp, vp, aob);

  dim3 g2(DMODEL / 128, (NB * LQ) / 128);  // 8 x 32 = 256 blocks
  hipLaunchKernelGGL(gemm_out, g2, dim3(256), 0, stream,
                     aob, wcb, bc, (float*)d_out, NB * LQ, DMODEL, DMODEL);
}

// Round 5
// 99.807 us; speedup vs baseline: 1.0416x; 1.0416x over previous
//
#include <hip/hip_runtime.h>
#include <hip/hip_bf16.h>
#include <stdint.h>

#define NB 2
#define LQ 2048
#define DMODEL 1024
#define NH 8
#define DH 128
#define KWIN 64

typedef __attribute__((ext_vector_type(8))) short short8;
typedef __attribute__((ext_vector_type(4))) float f32x4;

#define AS1 __attribute__((address_space(1)))
#define AS3 __attribute__((address_space(3)))

__device__ __forceinline__ ushort f2bf(float f) {
  uint u = __float_as_uint(f);
  return (ushort)((u + 0x7fffu + ((u >> 16) & 1u)) >> 16);
}
__device__ __forceinline__ float bflo(uint u) { return __uint_as_float(u << 16); }
__device__ __forceinline__ float bfhi(uint u) { return __uint_as_float(u & 0xffff0000u); }

// ---------------- merged f32 -> bf16 conversion (7 arrays, one launch) ----------------
__global__ void cvt_all(const float4* __restrict__ q, const float4* __restrict__ k,
                        const float4* __restrict__ v, const float4* __restrict__ wq,
                        const float4* __restrict__ wk, const float4* __restrict__ wv,
                        const float4* __restrict__ wc, ushort4* __restrict__ dst) {
  const int n4in = (NB * LQ * DMODEL) / 4;   // 2^20
  const int n4w = (NH * DH * DMODEL) / 4;    // 2^18
  const int total = 3 * n4in + 4 * n4w;
  const int stride = gridDim.x * blockDim.x;
  for (int i = blockIdx.x * blockDim.x + threadIdx.x; i < total; i += stride) {
    const float4* src;
    int off;
    if (i < 3 * n4in) {
      const int r = i >> 20;
      off = i & (n4in - 1);
      src = (r == 0) ? q : ((r == 1) ? k : v);
    } else {
      const int j = i - 3 * n4in;
      const int r = j >> 18;
      off = j & (n4w - 1);
      src = (r == 0) ? wq : ((r == 1) ? wk : ((r == 2) ? wv : wc));
    }
    float4 x = src[off];
    dst[i] = make_ushort4(f2bf(x.x), f2bf(x.y), f2bf(x.z), f2bf(x.w));
  }
}

// ---------------- QKV GEMM: 256x256 tile, BK=32, 4-slot ring, 2-phase/tile ----------------
// Per K-tile t: ph1 {stage(t+2,p0); vmcnt(6); barrier; 8 swz ds_read; lgkm0; prio 16 MFMA}
//               ph2 {stage(t+2,p1); 4 swz ds_read; lgkm0; prio 16 MFMA}
// LDS pair-row swizzle: elem(r,c8) at (r>>1)*64 + ((((c8<<1)|(r&1))^((r>>1)&7))*8) ushorts
// -> 16 lanes reading same c8 across rows hit each 16B slot exactly 2x (free, m136).
// Stage keeps LDS linear; global SOURCE pre-applies the inverse permutation (rule #21).
__global__ __launch_bounds__(512, 2) void gemm256p(
    const ushort* __restrict__ A0, const ushort* __restrict__ B0,
    const float* __restrict__ c0, ushort* __restrict__ D0,
    const ushort* __restrict__ A1, const ushort* __restrict__ B1,
    const float* __restrict__ c1, ushort* __restrict__ D1,
    const ushort* __restrict__ A2, const ushort* __restrict__ B2,
    const float* __restrict__ c2, ushort* __restrict__ D2,
    int M, int N, int Kd) {
  // XCD-chunked bijective swizzle over flat grid (192 blocks, 24/XCD)
  const int gx = gridDim.x, gy = gridDim.y;
  const int nblk = gx * gy * gridDim.z;
  const int fid = (blockIdx.z * gy + blockIdx.y) * gx + blockIdx.x;
  const int cpx = nblk >> 3;
  const int nid = (fid & 7) * cpx + (fid >> 3);
  const int z = nid / (gx * gy);
  const int rem = nid % (gx * gy);
  const int m0 = (rem / gx) * 256;
  const int n0 = (rem % gx) * 256;

  const ushort* A = (z == 0) ? A0 : ((z == 1) ? A1 : A2);
  const ushort* Bt = (z == 0) ? B0 : ((z == 1) ? B1 : B2);
  const float* bias = (z == 0) ? c0 : ((z == 1) ? c1 : c2);
  ushort* Cv = (z == 0) ? D0 : ((z == 1) ? D1 : D2);

  // slot: [A 8192 ushorts | B 8192 ushorts]; 4 slots = 128 KB
  __shared__ ushort LDS[4][16384];

  const int tid = threadIdx.x;
  const int wave = tid >> 6, lane = tid & 63;
  const int wm = wave >> 2, wn = wave & 3;
  const int lrow = lane & 15, kgrp = lane >> 4;

  // ---- staging precompute: 4 loads/thread/tile (A-lo, A-hi, B-lo, B-hi) ----
  const ushort* gsrc[4];
  int lofs[4];
#pragma unroll
  for (int qq = 0; qq < 4; ++qq) {
    const int half = qq & 1;
    const int o = half * 8192 + tid * 16;     // byte within 16KB region
    const int pr = o >> 7;                    // pair-row 0..127
    const int s = (o >> 4) & 7;               // 16B slot within 128B window
    const int x = s ^ (pr & 7);
    const int row = 2 * pr + (x & 1);         // source row 0..255
    const int chunk = (x >> 1) * 8;           // source k-elem base
    lofs[qq] = (qq >> 1) * 8192 + half * 4096 + tid * 8;
    gsrc[qq] = (qq < 2) ? (A + (size_t)(m0 + row) * Kd + chunk)
                        : (Bt + (size_t)(n0 + row) * Kd + chunk);
  }

  auto STAGE2 = [&](int tt, int p) {
    ushort* sl = &LDS[tt & 3][0];
    const int kt = tt << 5;
    __builtin_amdgcn_global_load_lds((const AS1 void*)(gsrc[p] + kt),
                                     (AS3 void*)(sl + lofs[p]), 16, 0, 0);
    __builtin_amdgcn_global_load_lds((const AS1 void*)(gsrc[2 + p] + kt),
                                     (AS3 void*)(sl + lofs[2 + p]), 16, 0, 0);
  };

  // ---- fragment read offsets (swizzled) ----
  int aoff[8], boff[4];
#pragma unroll
  for (int mi = 0; mi < 8; ++mi) {
    const int r = wm * 128 + mi * 16 + lrow;
    aoff[mi] = (r >> 1) * 64 + ((((kgrp << 1) | (r & 1)) ^ ((r >> 1) & 7)) * 8);
  }
#pragma unroll
  for (int ni = 0; ni < 4; ++ni) {
    const int r = wn * 64 + ni * 16 + lrow;
    boff[ni] = 8192 + (r >> 1) * 64 + ((((kgrp << 1) | (r & 1)) ^ ((r >> 1) & 7)) * 8);
  }

  f32x4 acc[8][4] = {};
  const int NT = Kd >> 5;  // 32

  STAGE2(0, 0); STAGE2(0, 1);
  STAGE2(1, 0); STAGE2(1, 1);

  for (int t = 0; t < NT; ++t) {
    const ushort* sl = &LDS[t & 3][0];
    // ---- phase 1 ----
    if (t < NT - 2) {
      STAGE2(t + 2, 0);
      asm volatile("s_waitcnt vmcnt(6)" ::: "memory");
    } else if (t == NT - 2) {
      asm volatile("s_waitcnt vmcnt(4)" ::: "memory");
    } else {
      asm volatile("s_waitcnt vmcnt(0)" ::: "memory");
    }
    __builtin_amdgcn_sched_barrier(0);
    __builtin_amdgcn_s_barrier();   // tile t fully staged & visible
    __builtin_amdgcn_sched_barrier(0);

    short8 af[8], bfr[4];
#pragma unroll
    for (int m = 0; m < 4; ++m) af[m] = *(const short8*)(sl + aoff[m]);
#pragma unroll
    for (int n = 0; n < 4; ++n) bfr[n] = *(const short8*)(sl + boff[n]);
    asm volatile("s_waitcnt lgkmcnt(0)" ::: "memory");
    __builtin_amdgcn_sched_barrier(0);
    __builtin_amdgcn_s_setprio(1);
#pragma unroll
    for (int m = 0; m < 4; ++m)
#pragma unroll
      for (int n = 0; n < 4; ++n)
        acc[m][n] = __builtin_amdgcn_mfma_f32_16x16x32_bf16(af[m], bfr[n], acc[m][n], 0, 0, 0);
    __builtin_amdgcn_s_setprio(0);
    __builtin_amdgcn_sched_barrier(0);

    // ---- phase 2 ----
    if (t < NT - 2) STAGE2(t + 2, 1);
#pragma unroll
    for (int m = 4; m < 8; ++m) af[m] = *(const short8*)(sl + aoff[m]);
    asm volatile("s_waitcnt lgkmcnt(0)" ::: "memory");
    __builtin_amdgcn_sched_barrier(0);
    __builtin_amdgcn_s_setprio(1);
#pragma unroll
    for (int m = 4; m < 8; ++m)
#pragma unroll
      for (int n = 0; n < 4; ++n)
        acc[m][n] = __builtin_amdgcn_mfma_f32_16x16x32_bf16(af[m], bfr[n], acc[m][n], 0, 0, 0);
    __builtin_amdgcn_s_setprio(0);
    __builtin_amdgcn_sched_barrier(0);
  }

  // epilogue: C/D layout col=lane&15, row=(lane>>4)*4+j
  const int cbase = n0 + wn * 64;
  const int rbase = m0 + wm * 128;
  float bv[4];
#pragma unroll
  for (int n = 0; n < 4; ++n) bv[n] = bias[cbase + n * 16 + lrow];

#pragma unroll
  for (int m = 0; m < 8; ++m) {
#pragma unroll
    for (int n = 0; n < 4; ++n) {
      const int col = cbase + n * 16 + lrow;
#pragma unroll
      for (int j = 0; j < 4; ++j) {
        const int row = rbase + m * 16 + kgrp * 4 + j;
        Cv[(size_t)row * N + col] = f2bf(acc[m][n][j] + bv[n]);
      }
    }
  }
}

// ---------------- out-proj GEMM: 128x128 tile, 2-phase dbuf (proven) ----------------
__global__ __launch_bounds__(256, 4) void gemm_out(
    const ushort* __restrict__ A, const ushort* __restrict__ Bt,
    const float* __restrict__ bias, float* __restrict__ Cv, int M, int N, int Kd) {
  const int gx = gridDim.x, gy = gridDim.y;
  const int nblk = gx * gy;
  const int fid = blockIdx.y * gx + blockIdx.x;
  const int cpx = nblk >> 3;
  const int nid = (fid & 7) * cpx + (fid >> 3);
  const int m0 = (nid / gx) * 128;
  const int n0 = (nid % gx) * 128;

  __shared__ ushort As[2][128 * 32];
  __shared__ ushort Bs[2][128 * 32];

  const int tid = threadIdx.x;
  const int wave = tid >> 6, lane = tid & 63;
  const int wm = wave >> 1, wn = wave & 1;
  const int lrow = lane & 15, kgrp = lane >> 4;

  const int b0 = tid * 16;
  const int b1 = b0 + 4096;
  const int r0 = b0 >> 6, cc0 = (b0 & 63) >> 1;
  const int r1 = b1 >> 6, cc1 = (b1 & 63) >> 1;

  const ushort* gA0 = A + (size_t)(m0 + r0) * Kd + cc0;
  const ushort* gA1 = A + (size_t)(m0 + r1) * Kd + cc1;
  const ushort* gB0 = Bt + (size_t)(n0 + r0) * Kd + cc0;
  const ushort* gB1 = Bt + (size_t)(n0 + r1) * Kd + cc1;

  auto stage = [&](int buf, int kt) {
    __builtin_amdgcn_global_load_lds((const AS1 void*)(gA0 + kt),
                                     (AS3 void*)(As[buf] + (b0 >> 1)), 16, 0, 0);
    __builtin_amdgcn_global_load_lds((const AS1 void*)(gA1 + kt),
                                     (AS3 void*)(As[buf] + (b1 >> 1)), 16, 0, 0);
    __builtin_amdgcn_global_load_lds((const AS1 void*)(gB0 + kt),
                                     (AS3 void*)(Bs[buf] + (b0 >> 1)), 16, 0, 0);
    __builtin_amdgcn_global_load_lds((const AS1 void*)(gB1 + kt),
                                     (AS3 void*)(Bs[buf] + (b1 >> 1)), 16, 0, 0);
  };

  f32x4 acc[4][4] = {};

  auto compute = [&](int buf) {
    short8 af[4], bfr[4];
#pragma unroll
    for (int m = 0; m < 4; ++m)
      af[m] = *(const short8*)(As[buf] + (wm * 64 + m * 16 + lrow) * 32 + kgrp * 8);
#pragma unroll
    for (int n = 0; n < 4; ++n)
      bfr[n] = *(const short8*)(Bs[buf] + (wn * 64 + n * 16 + lrow) * 32 + kgrp * 8);
#pragma unroll
    for (int m = 0; m < 4; ++m)
#pragma unroll
      for (int n = 0; n < 4; ++n)
        acc[m][n] = __builtin_amdgcn_mfma_f32_16x16x32_bf16(af[m], bfr[n], acc[m][n], 0, 0, 0);
  };

  const int nt = Kd >> 5;
  stage(0, 0);
  __syncthreads();
  int cur = 0;
  for (int it = 0; it < nt - 1; ++it) {
    stage(cur ^ 1, (it + 1) << 5);
    compute(cur);
    __syncthreads();
    cur ^= 1;
  }
  compute(cur);

  const int cbase = n0 + wn * 64;
  const int rbase = m0 + wm * 64;
  float bv[4];
#pragma unroll
  for (int n = 0; n < 4; ++n) bv[n] = bias[cbase + n * 16 + lrow];

#pragma unroll
  for (int m = 0; m < 4; ++m) {
#pragma unroll
    for (int n = 0; n < 4; ++n) {
      const int col = cbase + n * 16 + lrow;
#pragma unroll
      for (int j = 0; j < 4; ++j) {
        const int row = rbase + m * 16 + kgrp * 4 + j;
        Cv[(size_t)row * N + col] = acc[m][n][j] + bv[n];
      }
    }
  }
}

// ---------------- banded attention via residue-class MFMA flash ----------------
__global__ __launch_bounds__(128) void banded_attn_mfma(
    const ushort* __restrict__ qp, const ushort* __restrict__ kp,
    const ushort* __restrict__ vp, ushort* __restrict__ ao) {
  __shared__ ushort Qs[32 * 128];
  __shared__ ushort Ks[96 * 128];
  __shared__ ushort Vs[112 * 128];
  __shared__ ushort Ps[2][16 * 104];
  __shared__ ushort Os[2][16 * 128];

  const int tid = threadIdx.x;
  const int wv = tid >> 6;
  const int lane = tid & 63;
  const int lrow = lane & 15, kgrp = lane >> 4;

  const int blk = blockIdx.x;
  const int chunk = blk & 63;
  const int h = (blk >> 6) & 7;
  const int b = blk >> 9;
  const int sh = h >> 1;
  const int dil = 1 << sh;
  const int Ld = LQ >> sh;
  const int rres = chunk >> (6 - sh);
  const int tile = chunk & ((64 >> sh) - 1);
  const int t0 = tile << 5;
  const int p0 = t0 - 32;

  const size_t headoff = (size_t)h * DH;
  const size_t bbase = (size_t)b * LQ * (NH * DH);

  const int srow = lane >> 4;
  const int sc = lane & 15;
  for (int it = wv; it < 60; it += 2) {
    int rbase, pstart;
    const ushort* g;
    ushort* ld;
    if (it < 8) {
      rbase = it * 4; pstart = t0; g = qp; ld = Qs;
    } else if (it < 32) {
      rbase = (it - 8) * 4; pstart = p0; g = kp; ld = Ks;
    } else {
      rbase = (it - 32) * 4; pstart = p0; g = vp; ld = Vs;
    }
    int row = rbase + srow;
    int key = (row ^ (row >> 3)) & 7;
    int cs = sc ^ key;
    int t = pstart + row;
    t = t < 0 ? 0 : (t >= Ld ? Ld - 1 : t);
    int l = rres + t * dil;
    const ushort* src = g + bbase + (size_t)l * (NH * DH) + headoff + cs * 8;
    __builtin_amdgcn_global_load_lds((const AS1 void*)src,
                                     (AS3 void*)(ld + rbase * 128), 16, 0, 0);
  }
  __syncthreads();

  const int iblk = wv << 4;
  f32x4 accs[5] = {};
#pragma unroll
  for (int ks = 0; ks < 4; ++ks) {
    const int qrow = iblk + lrow;
    const int qslot = (ks * 4 + kgrp) ^ ((qrow ^ (qrow >> 3)) & 7);
    short8 qf = *(const short8*)(Qs + qrow * 128 + qslot * 8);
#pragma unroll
    for (int t = 0; t < 5; ++t) {
      const int krow = (wv + t) * 16 + lrow;
      const int kslot = (ks * 4 + kgrp) ^ ((krow ^ (krow >> 3)) & 7);
      short8 kf = *(const short8*)(Ks + krow * 128 + kslot * 8);
      accs[t] = __builtin_amdgcn_mfma_f32_16x16x32_bf16(qf, kf, accs[t], 0, 0, 0);
    }
  }

  float dens[4];
#pragma unroll
  for (int j = 0; j < 4; ++j) {
    const int i_b = iblk + kgrp * 4 + j;
    float mj = -1e30f;
#pragma unroll
    for (int t = 0; t < 5; ++t) {
      const int jj = (wv + t) * 16 + lrow;
      const int p = p0 + jj;
      const bool ok = (jj >= i_b + 1) && (jj <= i_b + 64) && (p >= 0) && (p < Ld);
      float v = ok ? accs[t][j] : -1e30f;
      accs[t][j] = v;
      mj = fmaxf(mj, v);
    }
#pragma unroll
    for (int off = 1; off < 16; off <<= 1) mj = fmaxf(mj, __shfl_xor(mj, off));
    float dj = 0.f;
#pragma unroll
    for (int t = 0; t < 5; ++t) {
      float e = __expf(accs[t][j] - mj);
      accs[t][j] = e;
      dj += e;
    }
#pragma unroll
    for (int off = 1; off < 16; off <<= 1) dj += __shfl_xor(dj, off);
    dens[j] = dj;
  }

  ushort* Pw = Ps[wv];
#pragma unroll
  for (int j = 0; j < 4; ++j) {
    const int prow = kgrp * 4 + j;
#pragma unroll
    for (int t = 0; t < 5; ++t) Pw[prow * 104 + t * 16 + lrow] = f2bf(accs[t][j]);
    Pw[prow * 104 + 80 + lrow] = 0;
  }

  f32x4 accv[8] = {};
#pragma unroll
  for (int ks = 0; ks < 3; ++ks) {
    short8 pf = *(const short8*)(Pw + lrow * 104 + ks * 32 + kgrp * 8);
#pragma unroll
    for (int dt = 0; dt < 8; ++dt) {
      short8 vf;
#pragma unroll
      for (int rr = 0; rr < 8; ++rr) {
        const int vrow = iblk + ks * 32 + kgrp * 8 + rr;
        const int d = dt * 16 + lrow;
        const int slot = (d >> 3) ^ ((vrow ^ (vrow >> 3)) & 7);
        vf[rr] = (short)Vs[vrow * 128 + slot * 8 + (d & 7)];
      }
      accv[dt] = __builtin_amdgcn_mfma_f32_16x16x32_bf16(pf, vf, accv[dt], 0, 0, 0);
    }
  }

  ushort* Ow = Os[wv];
#pragma unroll
  for (int j = 0; j < 4; ++j) {
    const float inv = 1.f / dens[j];
    const int orow = kgrp * 4 + j;
#pragma unroll
    for (int dt = 0; dt < 8; ++dt)
      Ow[orow * 128 + dt * 16 + lrow] = f2bf(accv[dt][j] * inv);
  }
#pragma unroll
  for (int pass = 0; pass < 4; ++pass) {
    const int i_loc = pass * 4 + srow;
    const int tq = t0 + iblk + i_loc;
    const int l = rres + tq * dil;
    short8 vvv = *(const short8*)(Ow + i_loc * 128 + sc * 8);
    *(short8*)(ao + bbase + (size_t)l * (NH * DH) + headoff + sc * 8) = vvv;
  }
}

// ---------------- launch ----------------
extern "C" void kernel_launch(void* const* d_in, const int* in_sizes, int n_in,
                              void* d_out, int out_size, void* d_ws, size_t ws_size,
                              hipStream_t stream) {
  const float* q = (const float*)d_in[0];
  const float* k = (const float*)d_in[1];
  const float* v = (const float*)d_in[2];
  const float* Wq = (const float*)d_in[3];
  const float* bq = (const float*)d_in[4];
  const float* Wk = (const float*)d_in[5];
  const float* bk = (const float*)d_in[6];
  const float* Wv = (const float*)d_in[7];
  const float* bv = (const float*)d_in[8];
  const float* Wc = (const float*)d_in[9];
  const float* bc = (const float*)d_in[10];

  const size_t NIN = (size_t)NB * LQ * DMODEL;
  const size_t NW = (size_t)NH * DH * DMODEL;

  ushort* qin = (ushort*)d_ws;
  ushort* kin = qin + NIN;
  ushort* vin = kin + NIN;
  ushort* wqb = vin + NIN;
  ushort* wkb = wqb + NW;
  ushort* wvb = wkb + NW;
  ushort* wcb = wvb + NW;
  ushort* qp = wcb + NW;
  ushort* kp = qp + NIN;
  ushort* vp = kp + NIN;
  ushort* aob = vp + NIN;

  hipLaunchKernelGGL(cvt_all, dim3(2048), dim3(256), 0, stream,
                     (const float4*)q, (const float4*)k, (const float4*)v,
                     (const float4*)Wq, (const float4*)Wk, (const float4*)Wv,
                     (const float4*)Wc, (ushort4*)qin);

  dim3 g1(DMODEL / 256, (NB * LQ) / 256, 3);  // 4 x 16 x 3 = 192 blocks
  hipLaunchKernelGGL(gemm256p, g1, dim3(512), 0, stream,
                     qin, wqb, bq, qp,
                     kin, wkb, bk, kp,
                     vin, wvb, bv, vp,
                     NB * LQ, DMODEL, DMODEL);

  hipLaunchKernelGGL(banded_attn_mfma, dim3(NB * NH * 64), dim3(128), 0, stream,
                     qp, kp, vp, aob);

  dim3 g2(DMODEL / 128, (NB * LQ) / 128);  // 8 x 32 = 256 blocks
  hipLaunchKernelGGL(gemm_out, g2, dim3(256), 0, stream,
                     aob, wcb, bc, (float*)d_out, NB * LQ, DMODEL, DMODEL);
}